// Round 11
// baseline (162.008 us; speedup 1.0000x reference)
//
#include <hip/hip_runtime.h>
#include <hip/hip_bf16.h>
#include <cstdint>

#define B_    8
#define C_    128
#define IC_   64
#define N_    2048
#define LOG2E 1.44269504088896340736f

typedef __attribute__((ext_vector_type(8))) short bf16x8;
typedef __attribute__((ext_vector_type(4))) float f32x4;

// workspace layout (float offsets)
#define OFF_FT   0          // B*N f32   (pre-scaled by log2e)
#define OFF_FP   16384      // B*N f32   (pre-scaled by log2e)
#define OFF_GXB  32768      // bf16 gxT [B][IC][N] = 2 MB

static __device__ __forceinline__ ushort f2bf(float f) {
  __hip_bfloat16 h = __float2bfloat16(f);
  return *reinterpret_cast<ushort*>(&h);
}

// ---------------------------------------------------------------------------
// K1: gxT[b][o][n] = bf16( sum_c g_w[o][c]*x[b][c][n] + g_b[o] )
//     f_t[b][n], f_p[b][n] (f32, scaled by log2e; cp_w folded in per-block)
// one block per (b, 64-n tile); 256 threads.  (~2 us measured-by-subtraction)
// ---------------------------------------------------------------------------
__global__ __launch_bounds__(256) void k_gx(const float* __restrict__ x,
                                            const float* __restrict__ g_w,
                                            const float* __restrict__ g_b,
                                            const float* __restrict__ theta_w,
                                            const float* __restrict__ theta_b,
                                            const float* __restrict__ phi_w,
                                            const float* __restrict__ phi_b,
                                            const float* __restrict__ cp_w,
                                            float* __restrict__ ws) {
  __shared__ float xs[C_][64];      // 32 KB
  __shared__ float wgT[C_][IC_];    // 32 KB
  __shared__ float vtp[2][C_];      // 1 KB   (vt, vp)
  __shared__ float fred[2][4][64];  // 2 KB   (ft/fp partials)
  __shared__ float fb[2];
  int bx = blockIdx.x;
  int b = bx >> 5, n0 = (bx & 31) * 64;
  int t = threadIdx.x;

  const float* xb = x + (size_t)b * C_ * N_ + n0;
  for (int idx = t; idx < C_ * 64; idx += 256) {
    int c = idx >> 6, n = idx & 63;
    xs[c][n] = xb[(size_t)c * N_ + n];
  }
  for (int idx = t; idx < C_ * IC_; idx += 256) {
    int c = idx >> 6, o = idx & 63;
    wgT[c][o] = g_w[o * C_ + c];
  }
  // fold cp_w into theta/phi (redundant per block, tiny)
  {
    int half = t >> 7;            // 0: theta, 1: phi
    int c = t & 127;
    const float* wmat = half ? phi_w : theta_w;
    const float* cw = cp_w + half * IC_;
    float a = 0.f;
#pragma unroll 8
    for (int o = 0; o < IC_; ++o) a += cw[o] * wmat[o * C_ + c];
    vtp[half][c] = a * LOG2E;
  }
  if (t < 2) {
    const float* bv = t ? phi_b : theta_b;
    const float* cw = cp_w + t * IC_;
    float a = 0.f;
    for (int o = 0; o < IC_; ++o) a += cw[o] * bv[o];
    fb[t] = a * LOG2E;
  }
  __syncthreads();

  // 4o x 4n register-blocked GEMM
  int o4 = (t & 15) * 4, n4 = (t >> 4) * 4;
  float acc[4][4] = {};
#pragma unroll 4
  for (int c = 0; c < C_; ++c) {
    float4 xv = *(const float4*)&xs[c][n4];
    float4 wv = *(const float4*)&wgT[c][o4];
    acc[0][0] += wv.x * xv.x; acc[0][1] += wv.x * xv.y; acc[0][2] += wv.x * xv.z; acc[0][3] += wv.x * xv.w;
    acc[1][0] += wv.y * xv.x; acc[1][1] += wv.y * xv.y; acc[1][2] += wv.y * xv.z; acc[1][3] += wv.y * xv.w;
    acc[2][0] += wv.z * xv.x; acc[2][1] += wv.z * xv.y; acc[2][2] += wv.z * xv.z; acc[2][3] += wv.z * xv.w;
    acc[3][0] += wv.w * xv.x; acc[3][1] += wv.w * xv.y; acc[3][2] += wv.w * xv.z; acc[3][3] += wv.w * xv.w;
  }
  __hip_bfloat16* gxT = (__hip_bfloat16*)(ws + OFF_GXB) + (size_t)b * IC_ * N_;
#pragma unroll
  for (int oo = 0; oo < 4; ++oo) {
    float gb = g_b[o4 + oo];
    ushort4 pk = make_ushort4(f2bf(acc[oo][0] + gb), f2bf(acc[oo][1] + gb),
                              f2bf(acc[oo][2] + gb), f2bf(acc[oo][3] + gb));
    *(ushort4*)(gxT + (size_t)(o4 + oo) * N_ + n0 + n4) = pk;
  }

  // f tail: 256 threads, 4-way c-split
  {
    int n = t & 63, qr = t >> 6;
    float ft = 0.f, fp = 0.f;
#pragma unroll 8
    for (int cc = 0; cc < 32; ++cc) {
      int c = qr * 32 + cc;
      float xv = xs[c][n];
      ft += xv * vtp[0][c];
      fp += xv * vtp[1][c];
    }
    fred[0][qr][n] = ft;
    fred[1][qr][n] = fp;
  }
  __syncthreads();
  if (t < 128) {
    int n = t & 63, isp = t >> 6;
    float f = fb[isp] + fred[isp][0][n] + fred[isp][1][n]
            + fred[isp][2][n] + fred[isp][3][n];
    ws[(isp ? OFF_FP : OFF_FT) + b * N_ + n0 + n] = f;
  }
}

// ---------------------------------------------------------------------------
// K2: fused attention, ZERO-LDS / ZERO-BARRIER. Block = (b, 32-row supertile),
// 256 threads = 4 independent waves: wave (w>>1) picks the 16-row half,
// (w&1) picks the 32-o-column half. Each lane computes its OWN MFMA
// A-fragment in registers: lane l -> P[row=l&15][j = ks*32 + (l>>4)*8 + i],
// so the softmax row is lane-local (no LDS exchange, no sync). P is computed
// 2x redundantly (once per o-half) -- bought back by fully independent waves.
// Row sums: lane-local partials -> shfl_xor(16,32) -> 4 shfl reads.
// ---------------------------------------------------------------------------
__global__ __launch_bounds__(256, 2) void k_attn(const int* __restrict__ adj,
                                                 const float* __restrict__ ws,
                                                 float* __restrict__ out) {
  int bx = blockIdx.x;
  int b = bx >> 6, st = bx & 63;          // 64 supertiles of 32 rows per b
  int t = threadIdx.x;
  int w = t >> 6, lane = t & 63;
  int col = lane & 15, agrp = lane >> 4;  // col: A-row AND B-col; agrp: k-subgroup
  int rowbase = st * 32 + (w >> 1) * 16;  // this wave's 16 P-rows (global i)
  int obase = (w & 1) * 32;               // this wave's 32 o-columns

  const float* f_t = ws + OFF_FT + b * N_;
  const float4* fpv = (const float4*)(ws + OFF_FP + b * N_);
  const __hip_bfloat16* gxT = (const __hip_bfloat16*)(ws + OFF_GXB) + (size_t)b * IC_ * N_;
  const __hip_bfloat16* gw0 = gxT + (size_t)(obase + col) * N_ + agrp * 8;
  const __hip_bfloat16* gw1 = gw0 + 16 * N_;

  float fti = f_t[rowbase + col];
  const int4*   arow = (const int4*)(adj + (size_t)(rowbase + col) * N_) + agrp * 2;
  const float4* fpl  = fpv + agrp * 2;

  f32x4 acc0 = {0.f, 0.f, 0.f, 0.f};
  f32x4 acc1 = {0.f, 0.f, 0.f, 0.f};
  float rsum = 0.f;

#pragma unroll 2
  for (int ks = 0; ks < 64; ++ks) {
    int4   a0 = arow[ks * 8];
    int4   a1 = arow[ks * 8 + 1];
    float4 f0 = fpl[ks * 8];
    float4 f1 = fpl[ks * 8 + 1];
    bf16x8 b0 = *(const bf16x8*)(gw0 + ks * 32);
    bf16x8 b1 = *(const bf16x8*)(gw1 + ks * 32);

    float s0 = fti + f0.x; s0 = fmaxf(s0, 0.2f * s0);
    float s1 = fti + f0.y; s1 = fmaxf(s1, 0.2f * s1);
    float s2 = fti + f0.z; s2 = fmaxf(s2, 0.2f * s2);
    float s3 = fti + f0.w; s3 = fmaxf(s3, 0.2f * s3);
    float s4 = fti + f1.x; s4 = fmaxf(s4, 0.2f * s4);
    float s5 = fti + f1.y; s5 = fmaxf(s5, 0.2f * s5);
    float s6 = fti + f1.z; s6 = fmaxf(s6, 0.2f * s6);
    float s7 = fti + f1.w; s7 = fmaxf(s7, 0.2f * s7);
    float p0 = (a0.x > 0) ? 0.f : exp2f(s0);
    float p1 = (a0.y > 0) ? 0.f : exp2f(s1);
    float p2 = (a0.z > 0) ? 0.f : exp2f(s2);
    float p3 = (a0.w > 0) ? 0.f : exp2f(s3);
    float p4 = (a1.x > 0) ? 0.f : exp2f(s4);
    float p5 = (a1.y > 0) ? 0.f : exp2f(s5);
    float p6 = (a1.z > 0) ? 0.f : exp2f(s6);
    float p7 = (a1.w > 0) ? 0.f : exp2f(s7);
    rsum += ((p0 + p1) + (p2 + p3)) + ((p4 + p5) + (p6 + p7));

    bf16x8 af;
    af[0] = (short)f2bf(p0); af[1] = (short)f2bf(p1);
    af[2] = (short)f2bf(p2); af[3] = (short)f2bf(p3);
    af[4] = (short)f2bf(p4); af[5] = (short)f2bf(p5);
    af[6] = (short)f2bf(p6); af[7] = (short)f2bf(p7);

    acc0 = __builtin_amdgcn_mfma_f32_16x16x32_bf16(af, b0, acc0, 0, 0, 0);
    acc1 = __builtin_amdgcn_mfma_f32_16x16x32_bf16(af, b1, acc1, 0, 0, 0);
  }

  // full row sums: combine the 4 k-subgroups holding the same row
  rsum += __shfl_xor(rsum, 16, 64);
  rsum += __shfl_xor(rsum, 32, 64);
  // D rows for this lane are agrp*4+q -> fetch those rows' sums (src lane = row)
  float r0 = __shfl(rsum, agrp * 4 + 0, 64);
  float r1 = __shfl(rsum, agrp * 4 + 1, 64);
  float r2 = __shfl(rsum, agrp * 4 + 2, 64);
  float r3 = __shfl(rsum, agrp * 4 + 3, 64);

  float4 res0 = make_float4(acc0[0] / r0, acc0[1] / r1, acc0[2] / r2, acc0[3] / r3);
  float4 res1 = make_float4(acc1[0] / r0, acc1[1] / r1, acc1[2] / r2, acc1[3] / r3);
  float* op = out + ((size_t)b * IC_ + obase + col) * N_ + rowbase + agrp * 4;
  *(float4*)op             = res0;
  *(float4*)(op + 16 * N_) = res1;
}

// ---------------------------------------------------------------------------
extern "C" void kernel_launch(void* const* d_in, const int* in_sizes, int n_in,
                              void* d_out, int out_size, void* d_ws, size_t ws_size,
                              hipStream_t stream) {
  const float* x       = (const float*)d_in[0];
  const int*   adj     = (const int*)  d_in[1];
  const float* g_w     = (const float*)d_in[2];
  const float* g_b     = (const float*)d_in[3];
  const float* theta_w = (const float*)d_in[4];
  const float* theta_b = (const float*)d_in[5];
  const float* phi_w   = (const float*)d_in[6];
  const float* phi_b   = (const float*)d_in[7];
  const float* cp_w    = (const float*)d_in[8];
  float* out = (float*)d_out;
  float* ws  = (float*)d_ws;

  k_gx<<<B_ * (N_ / 64), 256, 0, stream>>>(x, g_w, g_b, theta_w, theta_b,
                                           phi_w, phi_b, cp_w, ws);
  k_attn<<<B_ * (N_ / 32), 256, 0, stream>>>(adj, ws, out);
}

// Round 12
// 130.773 us; speedup vs baseline: 1.2389x; 1.2389x over previous
//
#include <hip/hip_runtime.h>
#include <hip/hip_bf16.h>
#include <cstdint>

#define B_    8
#define C_    128
#define IC_   64
#define N_    2048
#define LOG2E 1.44269504088896340736f

typedef __attribute__((ext_vector_type(8))) short bf16x8;
typedef __attribute__((ext_vector_type(4))) float f32x4;

// workspace layout (float offsets)
#define OFF_FT   0          // B*N f32   (pre-scaled by log2e)
#define OFF_FP   16384      // B*N f32   (pre-scaled by log2e)
#define OFF_GXB  32768      // bf16 gxT [B][IC][N] = 2 MB

static __device__ __forceinline__ ushort f2bf(float f) {
  __hip_bfloat16 h = __float2bfloat16(f);
  return *reinterpret_cast<ushort*>(&h);
}

// ---------------------------------------------------------------------------
// K1: gxT[b][o][n] = bf16( sum_c g_w[o][c]*x[b][c][n] + g_b[o] )
//     f_t[b][n], f_p[b][n] (f32, scaled by log2e; cp_w folded in per-block)
// one block per (b, 64-n tile); 256 threads.  (~2 us measured-by-subtraction)
// ---------------------------------------------------------------------------
__global__ __launch_bounds__(256) void k_gx(const float* __restrict__ x,
                                            const float* __restrict__ g_w,
                                            const float* __restrict__ g_b,
                                            const float* __restrict__ theta_w,
                                            const float* __restrict__ theta_b,
                                            const float* __restrict__ phi_w,
                                            const float* __restrict__ phi_b,
                                            const float* __restrict__ cp_w,
                                            float* __restrict__ ws) {
  __shared__ float xs[C_][64];      // 32 KB
  __shared__ float wgT[C_][IC_];    // 32 KB
  __shared__ float vtp[2][C_];      // 1 KB   (vt, vp)
  __shared__ float fred[2][4][64];  // 2 KB   (ft/fp partials)
  __shared__ float fb[2];
  int bx = blockIdx.x;
  int b = bx >> 5, n0 = (bx & 31) * 64;
  int t = threadIdx.x;

  const float* xb = x + (size_t)b * C_ * N_ + n0;
  for (int idx = t; idx < C_ * 64; idx += 256) {
    int c = idx >> 6, n = idx & 63;
    xs[c][n] = xb[(size_t)c * N_ + n];
  }
  for (int idx = t; idx < C_ * IC_; idx += 256) {
    int c = idx >> 6, o = idx & 63;
    wgT[c][o] = g_w[o * C_ + c];
  }
  // fold cp_w into theta/phi (redundant per block, tiny)
  {
    int half = t >> 7;            // 0: theta, 1: phi
    int c = t & 127;
    const float* wmat = half ? phi_w : theta_w;
    const float* cw = cp_w + half * IC_;
    float a = 0.f;
#pragma unroll 8
    for (int o = 0; o < IC_; ++o) a += cw[o] * wmat[o * C_ + c];
    vtp[half][c] = a * LOG2E;
  }
  if (t < 2) {
    const float* bv = t ? phi_b : theta_b;
    const float* cw = cp_w + t * IC_;
    float a = 0.f;
    for (int o = 0; o < IC_; ++o) a += cw[o] * bv[o];
    fb[t] = a * LOG2E;
  }
  __syncthreads();

  // 4o x 4n register-blocked GEMM
  int o4 = (t & 15) * 4, n4 = (t >> 4) * 4;
  float acc[4][4] = {};
#pragma unroll 4
  for (int c = 0; c < C_; ++c) {
    float4 xv = *(const float4*)&xs[c][n4];
    float4 wv = *(const float4*)&wgT[c][o4];
    acc[0][0] += wv.x * xv.x; acc[0][1] += wv.x * xv.y; acc[0][2] += wv.x * xv.z; acc[0][3] += wv.x * xv.w;
    acc[1][0] += wv.y * xv.x; acc[1][1] += wv.y * xv.y; acc[1][2] += wv.y * xv.z; acc[1][3] += wv.y * xv.w;
    acc[2][0] += wv.z * xv.x; acc[2][1] += wv.z * xv.y; acc[2][2] += wv.z * xv.z; acc[2][3] += wv.z * xv.w;
    acc[3][0] += wv.w * xv.x; acc[3][1] += wv.w * xv.y; acc[3][2] += wv.w * xv.z; acc[3][3] += wv.w * xv.w;
  }
  __hip_bfloat16* gxT = (__hip_bfloat16*)(ws + OFF_GXB) + (size_t)b * IC_ * N_;
#pragma unroll
  for (int oo = 0; oo < 4; ++oo) {
    float gb = g_b[o4 + oo];
    ushort4 pk = make_ushort4(f2bf(acc[oo][0] + gb), f2bf(acc[oo][1] + gb),
                              f2bf(acc[oo][2] + gb), f2bf(acc[oo][3] + gb));
    *(ushort4*)(gxT + (size_t)(o4 + oo) * N_ + n0 + n4) = pk;
  }

  // f tail: 256 threads, 4-way c-split
  {
    int n = t & 63, qr = t >> 6;
    float ft = 0.f, fp = 0.f;
#pragma unroll 8
    for (int cc = 0; cc < 32; ++cc) {
      int c = qr * 32 + cc;
      float xv = xs[c][n];
      ft += xv * vtp[0][c];
      fp += xv * vtp[1][c];
    }
    fred[0][qr][n] = ft;
    fred[1][qr][n] = fp;
  }
  __syncthreads();
  if (t < 128) {
    int n = t & 63, isp = t >> 6;
    float f = fb[isp] + fred[isp][0][n] + fred[isp][1][n]
            + fred[isp][2][n] + fred[isp][3][n];
    ws[(isp ? OFF_FP : OFF_FT) + b * N_ + n0 + n] = f;
  }
}

// ---------------------------------------------------------------------------
// K2: fused attention, j-split flash. Block = (b, 16-row tile), 128 threads
// = 2 waves; wave w owns j in [w*1024, w*1024+1024) and ALL 64 o (1x P!).
// Per 64-j window: coalesced adj staging (4 rows x 256B per int4 load) ->
// exp2 -> bf16 P into wave-PRIVATE XOR-swizzled LDS (no barrier, lgkmcnt
// only) -> 2 ds_read_b128 A-frags -> 8 MFMA. Explicit next-window prefetch
// in rotated registers forces ~13 loads in flight (r11's VGPR=36 showed the
// compiler otherwise serializes). One __syncthreads total (j-half merge:
// no softmax max-rescale, so merge = add accs + add rowsums).
// ---------------------------------------------------------------------------
__global__ __launch_bounds__(128, 2) void k_attn(const int* __restrict__ adj,
                                                 const float* __restrict__ ws,
                                                 float* __restrict__ out) {
  __shared__ char pstage[2][2][2048];   // [wave][dbuf][16r x 64j bf16, swizzled]
  __shared__ float mrg[64][20];         // wave1 -> wave0: 16 acc + 4 rowsum
  __shared__ float rsm[16];             // final rowsums (wave0 only)

  int bx = blockIdx.x;
  int b = bx >> 7, rt = bx & 127;
  int rowbase = rt * 16;
  int t = threadIdx.x;
  int wid = t >> 6, lane = t & 63;
  int c16 = lane & 15, g8 = lane >> 4;  // c16: j-lane / A-row / B-col; g8: row-group / k-group
  int jbase = wid * 1024;

  const float* f_t = ws + OFF_FT + b * N_;
  const float* f_p = ws + OFF_FP + b * N_ + jbase + c16 * 4;
  const __hip_bfloat16* gxT = (const __hip_bfloat16*)(ws + OFF_GXB) + (size_t)b * IC_ * N_;

  float fti[4];
#pragma unroll
  for (int rr = 0; rr < 4; ++rr) fti[rr] = f_t[rowbase + rr * 4 + g8];

  const int* arow0 = adj + (size_t)(rowbase + g8) * N_ + jbase + c16 * 4;       // + rr*4*N_
  const __hip_bfloat16* gw0 = gxT + (size_t)c16 * N_ + jbase + g8 * 8;          // + ot*16*N_

  // ---- preload window 0 ----
  int4 ca[4]; float4 cf; bf16x8 cg[8];
#pragma unroll
  for (int rr = 0; rr < 4; ++rr) ca[rr] = *(const int4*)(arow0 + (size_t)rr * 4 * N_);
  cf = *(const float4*)(f_p);
#pragma unroll
  for (int ot = 0; ot < 4; ++ot) {
    cg[ot * 2 + 0] = *(const bf16x8*)(gw0 + (size_t)ot * 16 * N_);
    cg[ot * 2 + 1] = *(const bf16x8*)(gw0 + (size_t)ot * 16 * N_ + 32);
  }

  f32x4 acc[4];
#pragma unroll
  for (int ot = 0; ot < 4; ++ot) acc[ot] = (f32x4){0.f, 0.f, 0.f, 0.f};
  float rsum[4] = {0.f, 0.f, 0.f, 0.f};

  for (int w = 0; w < 16; ++w) {
    int nw = (w < 15) ? w + 1 : 15;   // clamp: last iter reloads (dead, DCE'd)
    // ---- issue next-window loads (rotated regs -> guaranteed in flight) ----
    int4 na[4]; float4 nf; bf16x8 ng[8];
#pragma unroll
    for (int rr = 0; rr < 4; ++rr)
      na[rr] = *(const int4*)(arow0 + (size_t)rr * 4 * N_ + nw * 64);
    nf = *(const float4*)(f_p + nw * 64);
#pragma unroll
    for (int ot = 0; ot < 4; ++ot) {
      ng[ot * 2 + 0] = *(const bf16x8*)(gw0 + (size_t)ot * 16 * N_ + nw * 64);
      ng[ot * 2 + 1] = *(const bf16x8*)(gw0 + (size_t)ot * 16 * N_ + nw * 64 + 32);
    }

    // ---- stage P window w: rows rr*4+g8, j-local c16*4..+3 ----
    char* pb = pstage[wid][w & 1];
#pragma unroll
    for (int rr = 0; rr < 4; ++rr) {
      int4 a = ca[rr];
      float ft = fti[rr];
      float s0 = ft + cf.x; s0 = fmaxf(s0, 0.2f * s0);
      float s1 = ft + cf.y; s1 = fmaxf(s1, 0.2f * s1);
      float s2 = ft + cf.z; s2 = fmaxf(s2, 0.2f * s2);
      float s3 = ft + cf.w; s3 = fmaxf(s3, 0.2f * s3);
      float p0 = (a.x > 0) ? 0.f : exp2f(s0);
      float p1 = (a.y > 0) ? 0.f : exp2f(s1);
      float p2 = (a.z > 0) ? 0.f : exp2f(s2);
      float p3 = (a.w > 0) ? 0.f : exp2f(s3);
      rsum[rr] += (p0 + p1) + (p2 + p3);
      ushort4 pk = make_ushort4(f2bf(p0), f2bf(p1), f2bf(p2), f2bf(p3));
      int row = rr * 4 + g8;
      int byte = (row * 128 + c16 * 8) ^ ((row & 7) << 4);
      *(ushort4*)(pb + byte) = pk;
    }

    // ---- A-frag reads (within-wave lgkmcnt, no barrier) + 8 MFMA ----
#pragma unroll
    for (int ks = 0; ks < 2; ++ks) {
      int rbyte = (c16 * 128 + ks * 64 + g8 * 16) ^ ((c16 & 7) << 4);
      bf16x8 af = *(const bf16x8*)(pb + rbyte);
      acc[0] = __builtin_amdgcn_mfma_f32_16x16x32_bf16(af, cg[0 * 2 + ks], acc[0], 0, 0, 0);
      acc[1] = __builtin_amdgcn_mfma_f32_16x16x32_bf16(af, cg[1 * 2 + ks], acc[1], 0, 0, 0);
      acc[2] = __builtin_amdgcn_mfma_f32_16x16x32_bf16(af, cg[2 * 2 + ks], acc[2], 0, 0, 0);
      acc[3] = __builtin_amdgcn_mfma_f32_16x16x32_bf16(af, cg[3 * 2 + ks], acc[3], 0, 0, 0);
    }

    // ---- rotate ----
#pragma unroll
    for (int rr = 0; rr < 4; ++rr) ca[rr] = na[rr];
    cf = nf;
#pragma unroll
    for (int i = 0; i < 8; ++i) cg[i] = ng[i];
  }

  // ---- rowsum: reduce over the 16 j-lanes (bits 0-3) ----
#pragma unroll
  for (int rr = 0; rr < 4; ++rr) {
    rsum[rr] += __shfl_xor(rsum[rr], 1, 64);
    rsum[rr] += __shfl_xor(rsum[rr], 2, 64);
    rsum[rr] += __shfl_xor(rsum[rr], 4, 64);
    rsum[rr] += __shfl_xor(rsum[rr], 8, 64);
  }

  // ---- j-half merge (the ONLY barrier) ----
  if (wid == 1) {
#pragma unroll
    for (int ot = 0; ot < 4; ++ot) *(f32x4*)&mrg[lane][ot * 4] = acc[ot];
    *(f32x4*)&mrg[lane][16] = (f32x4){rsum[0], rsum[1], rsum[2], rsum[3]};
  }
  __syncthreads();
  if (wid == 0) {
#pragma unroll
    for (int ot = 0; ot < 4; ++ot) {
      f32x4 o1 = *(const f32x4*)&mrg[lane][ot * 4];
      acc[ot][0] += o1[0]; acc[ot][1] += o1[1];
      acc[ot][2] += o1[2]; acc[ot][3] += o1[3];
    }
    f32x4 r1 = *(const f32x4*)&mrg[lane][16];
    rsum[0] += r1[0]; rsum[1] += r1[1]; rsum[2] += r1[2]; rsum[3] += r1[3];

    // publish rowsums rows rr*4+g8 (writer: c16==0), read back as float4
    if (c16 == 0) {
      rsm[0 * 4 + g8] = rsum[0]; rsm[1 * 4 + g8] = rsum[1];
      rsm[2 * 4 + g8] = rsum[2]; rsm[3 * 4 + g8] = rsum[3];
    }
    float4 rs4 = *(const float4*)&rsm[g8 * 4];   // rows g8*4..+3 = D rows

    // store: out[b][o][rowbase + g8*4 .. +3], o = ot*16 + c16
#pragma unroll
    for (int ot = 0; ot < 4; ++ot) {
      float* op = out + ((size_t)b * IC_ + ot * 16 + c16) * N_ + rowbase + g8 * 4;
      *(float4*)op = make_float4(acc[ot][0] / rs4.x, acc[ot][1] / rs4.y,
                                 acc[ot][2] / rs4.z, acc[ot][3] / rs4.w);
    }
  }
}

// ---------------------------------------------------------------------------
extern "C" void kernel_launch(void* const* d_in, const int* in_sizes, int n_in,
                              void* d_out, int out_size, void* d_ws, size_t ws_size,
                              hipStream_t stream) {
  const float* x       = (const float*)d_in[0];
  const int*   adj     = (const int*)  d_in[1];
  const float* g_w     = (const float*)d_in[2];
  const float* g_b     = (const float*)d_in[3];
  const float* theta_w = (const float*)d_in[4];
  const float* theta_b = (const float*)d_in[5];
  const float* phi_w   = (const float*)d_in[6];
  const float* phi_b   = (const float*)d_in[7];
  const float* cp_w    = (const float*)d_in[8];
  float* out = (float*)d_out;
  float* ws  = (float*)d_ws;

  k_gx<<<B_ * (N_ / 64), 256, 0, stream>>>(x, g_w, g_b, theta_w, theta_b,
                                           phi_w, phi_b, cp_w, ws);
  k_attn<<<B_ * (N_ / 16), 128, 0, stream>>>(adj, ws, out);
}